// Round 13
// baseline (180.249 us; speedup 1.0000x reference)
//
#include <hip/hip_runtime.h>

#define CPG 8
#define NGRP 32
#define NB 16
#define HW 3136
#define HU 784       // float4 units per channel image
#define N2 36
#define N3 120
#define NF 165       // 164 poly features + 1 summed-bias row
#define WSTRIDE (NF * CPG)   // 1320 floats per group in ws (5280 B, 16B-aligned)

typedef float vfloat4 __attribute__((ext_vector_type(4)));

__host__ __device__ constexpr int idx2(int i, int j) {
    return i * CPG - i * (i - 1) / 2 + (j - i);
}
__host__ __device__ constexpr int idx3(int a, int b, int c) {
    int base = 0;
    for (int t = 0; t < a; ++t) { int m = CPG - t; base += m * (m + 1) / 2; }
    for (int t = a; t < b; ++t) base += CPG - t;
    return base + (c - b);
}

__device__ inline vfloat4 splat4(float s) { return (vfloat4){s, s, s, s}; }

// ---------------------------------------------------------------------------
// prep: transpose weights to ws[g][f][o] (f-major, 8 contiguous outputs per
// feature, two 16B-aligned vec4 per feature).
// f 0-7: deg1, 8-43: deg2, 44-163: deg3, 164: b1+b2+b3
// ---------------------------------------------------------------------------
__global__ __launch_bounds__(256) void prep_weights(
    const float* __restrict__ w1, const float* __restrict__ b1,
    const float* __restrict__ w2, const float* __restrict__ b2,
    const float* __restrict__ w3, const float* __restrict__ b3,
    float* __restrict__ ws)
{
    const int g = blockIdx.x;
    for (int idx = threadIdx.x; idx < WSTRIDE; idx += 256) {
        const int f = idx >> 3, o = idx & 7;
        const int ch = g * CPG + o;
        float v;
        if (f < 8)        v = w1[ch * CPG + f];
        else if (f < 44)  v = w2[ch * N2 + (f - 8)];
        else if (f < 164) v = w3[ch * N3 + (f - 44)];
        else              v = b1[ch] + b2[ch] + b3[ch];
        ws[g * WSTRIDE + idx] = v;
    }
}

// Weights via VECTOR loads (vmcnt: counted, in-order, compiler-pipelined),
// not SMEM (out-of-order -> lgkmcnt(0) batch-drain convoys, the R11 stall).
// All 64 lanes load the same address -> one broadcast vL1 line (weights
// 5.3 KB/group, L1-resident).
#define ACCUMV(F, T) do {                                                    \
    const vfloat4 wa = wv[(F) * 2 + 0];                                      \
    const vfloat4 wb = wv[(F) * 2 + 1];                                      \
    acc[0] += wa.x * (T); acc[1] += wa.y * (T);                              \
    acc[2] += wa.z * (T); acc[3] += wa.w * (T);                              \
    acc[4] += wb.x * (T); acc[5] += wb.y * (T);                              \
    acc[6] += wb.z * (T); acc[7] += wb.w * (T);                              \
} while (0)

// scheduler fence per (i,j) group: bounds in-flight weight loads (R3-proven)
#define FENCE() __builtin_amdgcn_sched_barrier(0)

__global__ __launch_bounds__(256, 2) void hoaf_vec(
    const float* __restrict__ x,
    const float* __restrict__ ws,
    float* __restrict__ out)
{
    const int tid   = threadIdx.x;
    const int g     = blockIdx.x;   // block-uniform group
    const int b     = blockIdx.y;
    const int chunk = blockIdx.z;   // 0..3; chunk 3 is a 16-unit runt

    const int q = tid + chunk * 256;   // one float4 body per thread
    if (q >= HU) return;

    // opaque zero in a VGPR: weight address is formally non-uniform ->
    // compiler MUST use vector loads (global_load_dwordx4), not s_load.
    int z0;
    asm("v_mov_b32 %0, 0" : "=v"(z0));
    const vfloat4* __restrict__ wv =
        (const vfloat4*)(ws + (size_t)g * WSTRIDE) + z0;

    const size_t base = ((size_t)(b * NGRP + g) * CPG) * HW;
    const vfloat4* x4 = (const vfloat4*)(x + base);
    vfloat4*       o4 = (vfloat4*)(out + base);

    vfloat4 xv[CPG];
#pragma unroll
    for (int c = 0; c < CPG; ++c) xv[c] = x4[(size_t)c * HU + q];
    // Pin xv in registers: asm output cannot be rematerialized. This is the
    // fix for VGPR_Count=40-52 < the 64-reg array set seen in R3/R11/R12 —
    // the allocator was re-loading xv from memory per (i,j) group all session.
#pragma unroll
    for (int c = 0; c < CPG; ++c) asm volatile("" : "+v"(xv[c]));

    const vfloat4 b_lo = wv[164 * 2 + 0];
    const vfloat4 b_hi = wv[164 * 2 + 1];

    vfloat4 acc[CPG];
    acc[0] = splat4(b_lo.x); acc[1] = splat4(b_lo.y);
    acc[2] = splat4(b_lo.z); acc[3] = splat4(b_lo.w);
    acc[4] = splat4(b_hi.x); acc[5] = splat4(b_hi.y);
    acc[6] = splat4(b_hi.z); acc[7] = splat4(b_hi.w);

    // degree 1, fenced every 2 features
#pragma unroll
    for (int k = 0; k < CPG; k += 2) {
        ACCUMV(k, xv[k]);
        ACCUMV(k + 1, xv[k + 1]);
        FENCE();
    }

    // degree 2 & 3: pair product (i<=j) feeds triples (a<=i<=j)
#pragma unroll
    for (int i = 0; i < CPG; ++i) {
#pragma unroll
        for (int j = i; j < CPG; ++j) {
            const vfloat4 p = xv[i] * xv[j];
            ACCUMV(8 + idx2(i, j), p);
#pragma unroll
            for (int a = 0; a <= i; ++a) {
                const vfloat4 t = xv[a] * p;
                ACCUMV(44 + idx3(a, i, j), t);
            }
            FENCE();
        }
    }

#pragma unroll
    for (int o = 0; o < CPG; ++o) o4[(size_t)o * HU + q] = acc[o];
}

// ---------------------------------------------------------------------------
// Fallback (workspace too small): R3 kernel verbatim — known-good 68.5 us.
// ---------------------------------------------------------------------------
#define ACCUM(F, T) do {                                                       \
    const vfloat4 wa = *reinterpret_cast<const vfloat4*>(&wt[(F)][0]);         \
    const vfloat4 wb = *reinterpret_cast<const vfloat4*>(&wt[(F)][4]);         \
    acc[0] += wa.x * (T); acc[1] += wa.y * (T);                                \
    acc[2] += wa.z * (T); acc[3] += wa.w * (T);                                \
    acc[4] += wb.x * (T); acc[5] += wb.y * (T);                                \
    acc[6] += wb.z * (T); acc[7] += wb.w * (T);                                \
} while (0)

__global__ __launch_bounds__(256, 4) void hoaf_lds(
    const float* __restrict__ x,
    const float* __restrict__ w1, const float* __restrict__ b1,
    const float* __restrict__ w2, const float* __restrict__ b2,
    const float* __restrict__ w3, const float* __restrict__ b3,
    float* __restrict__ out)
{
    __shared__ __align__(16) float wt[165][8];

    const int tid   = threadIdx.x;
    const int g     = blockIdx.x;
    const int b     = blockIdx.y;
    const int chunk = blockIdx.z;

    for (int idx = tid; idx < 165 * 8; idx += 256) {
        const int f = idx >> 3, o = idx & 7;
        const int ch = g * CPG + o;
        float v;
        if (f < 8)        v = w1[ch * CPG + f];
        else if (f < 44)  v = w2[ch * N2 + (f - 8)];
        else if (f < 164) v = w3[ch * N3 + (f - 44)];
        else              v = b1[ch] + b2[ch] + b3[ch];
        wt[f][o] = v;
    }
    __syncthreads();

    const int q = tid + chunk * 256;
    if (q >= HU) return;

    const vfloat4 b_lo = *reinterpret_cast<const vfloat4*>(&wt[164][0]);
    const vfloat4 b_hi = *reinterpret_cast<const vfloat4*>(&wt[164][4]);

    const size_t base = ((size_t)(b * NGRP + g) * CPG) * HW;
    const vfloat4* x4 = (const vfloat4*)(x + base);
    vfloat4*       o4 = (vfloat4*)(out + base);

    vfloat4 xv[CPG];
#pragma unroll
    for (int c = 0; c < CPG; ++c) xv[c] = x4[(size_t)c * HU + q];

    vfloat4 acc[CPG];
    acc[0] = splat4(b_lo.x); acc[1] = splat4(b_lo.y);
    acc[2] = splat4(b_lo.z); acc[3] = splat4(b_lo.w);
    acc[4] = splat4(b_hi.x); acc[5] = splat4(b_hi.y);
    acc[6] = splat4(b_hi.z); acc[7] = splat4(b_hi.w);

#pragma unroll
    for (int k = 0; k < CPG; k += 2) {
        ACCUM(k, xv[k]);
        ACCUM(k + 1, xv[k + 1]);
        FENCE();
    }

#pragma unroll
    for (int i = 0; i < CPG; ++i) {
#pragma unroll
        for (int j = i; j < CPG; ++j) {
            const vfloat4 p = xv[i] * xv[j];
            ACCUM(8 + idx2(i, j), p);
#pragma unroll
            for (int a = 0; a <= i; ++a) {
                const vfloat4 t = xv[a] * p;
                ACCUM(44 + idx3(a, i, j), t);
            }
            FENCE();
        }
    }

#pragma unroll
    for (int o = 0; o < CPG; ++o) o4[(size_t)o * HU + q] = acc[o];
}

extern "C" void kernel_launch(void* const* d_in, const int* in_sizes, int n_in,
                              void* d_out, int out_size, void* d_ws, size_t ws_size,
                              hipStream_t stream) {
    const float* x  = (const float*)d_in[0];
    const float* w1 = (const float*)d_in[1];
    const float* b1 = (const float*)d_in[2];
    const float* w2 = (const float*)d_in[3];
    const float* b2 = (const float*)d_in[4];
    const float* w3 = (const float*)d_in[5];
    const float* b3 = (const float*)d_in[6];
    float* out = (float*)d_out;
    float* ws  = (float*)d_ws;

    dim3 grid(NGRP, NB, 4);   // (group, batch, pixel-chunk) — chunk slowest
    dim3 block(256);

    const size_t ws_needed = (size_t)NGRP * WSTRIDE * sizeof(float);  // 169 KB
    if (ws != nullptr && ws_size >= ws_needed) {
        prep_weights<<<dim3(NGRP), dim3(256), 0, stream>>>(w1, b1, w2, b2, w3, b3, ws);
        hoaf_vec<<<grid, block, 0, stream>>>(x, ws, out);
    } else {
        hoaf_lds<<<grid, block, 0, stream>>>(x, w1, b1, w2, b2, w3, b3, out);
    }
}

// Round 14
// 149.305 us; speedup vs baseline: 1.2073x; 1.2073x over previous
//
#include <hip/hip_runtime.h>

#define CPG 8
#define NGRP 32
#define NB 16
#define HW 3136
#define HU 784       // float4 units per channel image
#define N2 36
#define N3 120
#define NF 165       // 164 poly features + 1 summed-bias row
#define WSTRIDE (NF * CPG)   // 1320 floats per group in ws

typedef float vfloat4 __attribute__((ext_vector_type(4)));

__host__ __device__ constexpr int idx2(int i, int j) {
    return i * CPG - i * (i - 1) / 2 + (j - i);
}
__host__ __device__ constexpr int idx3(int a, int b, int c) {
    int base = 0;
    for (int t = 0; t < a; ++t) { int m = CPG - t; base += m * (m + 1) / 2; }
    for (int t = a; t < b; ++t) base += CPG - t;
    return base + (c - b);
}

__device__ inline vfloat4 splat4(float s) { return (vfloat4){s, s, s, s}; }

// ---------------------------------------------------------------------------
// prep: transpose weights to ws[g][f][o] (f-major, 8 contiguous outputs per
// feature) -> main kernel reads one s_load_dwordx8 per feature.
// f 0-7: deg1, 8-43: deg2, 44-163: deg3, 164: b1+b2+b3
// ---------------------------------------------------------------------------
__global__ __launch_bounds__(256) void prep_weights(
    const float* __restrict__ w1, const float* __restrict__ b1,
    const float* __restrict__ w2, const float* __restrict__ b2,
    const float* __restrict__ w3, const float* __restrict__ b3,
    float* __restrict__ ws)
{
    const int g = blockIdx.x;
    for (int idx = threadIdx.x; idx < WSTRIDE; idx += 256) {
        const int f = idx >> 3, o = idx & 7;
        const int ch = g * CPG + o;
        float v;
        if (f < 8)        v = w1[ch * CPG + f];
        else if (f < 44)  v = w2[ch * N2 + (f - 8)];
        else if (f < 164) v = w3[ch * N3 + (f - 44)];
        else              v = b1[ch] + b2[ch] + b3[ch];
        ws[g * WSTRIDE + idx] = v;
    }
}

// weights on the SCALAR pipe (R11-proven best: 61.5us) — uniform address,
// contiguous dwordx8 per feature; v_fmac v,s,v takes the scalar directly.
#define ACCUMS(F, T) do {                                                    \
    const float w0 = wp[(F) * 8 + 0], w1_ = wp[(F) * 8 + 1];                 \
    const float w2_ = wp[(F) * 8 + 2], w3_ = wp[(F) * 8 + 3];                \
    const float w4_ = wp[(F) * 8 + 4], w5_ = wp[(F) * 8 + 5];                \
    const float w6_ = wp[(F) * 8 + 6], w7_ = wp[(F) * 8 + 7];                \
    acc[0] += w0  * (T); acc[1] += w1_ * (T);                                \
    acc[2] += w2_ * (T); acc[3] += w3_ * (T);                                \
    acc[4] += w4_ * (T); acc[5] += w5_ * (T);                                \
    acc[6] += w6_ * (T); acc[7] += w7_ * (T);                                \
} while (0)

// R11 + xv register pin (R13-proven: VGPR 44->88, pin engages, no spill).
// R11's VGPR_Count=44 < the 64-reg xv+acc set => allocator was re-loading xv
// from L1/L2 per (i,j) group (invisible in FETCH: HBM-only counter). The asm
// identity makes xv an asm output — rematerialization impossible.
__global__ __launch_bounds__(256, 2) void hoaf_sload(
    const float* __restrict__ x,
    const float* __restrict__ ws,
    float* __restrict__ out)
{
    const int tid   = threadIdx.x;
    const int g     = blockIdx.x;   // block-uniform group
    const int b     = blockIdx.y;
    const int chunk = blockIdx.z;   // 0..3; chunk 3 is a 16-unit runt

    const int q = tid + chunk * 256;   // one float4 body per thread
    if (q >= HU) return;

    const float* __restrict__ wp = ws + g * WSTRIDE;  // uniform -> s_load

    const size_t base = ((size_t)(b * NGRP + g) * CPG) * HW;
    const vfloat4* x4 = (const vfloat4*)(x + base);
    vfloat4*       o4 = (vfloat4*)(out + base);

    vfloat4 xv[CPG];
#pragma unroll
    for (int c = 0; c < CPG; ++c) xv[c] = x4[(size_t)c * HU + q];
    // pin: forbid rematerialization/re-load of xv (R3..R12 pathology)
#pragma unroll
    for (int c = 0; c < CPG; ++c) asm volatile("" : "+v"(xv[c]));

    vfloat4 acc[CPG];
#pragma unroll
    for (int o = 0; o < CPG; ++o) acc[o] = splat4(wp[164 * 8 + o]);

    // degree 1
#pragma unroll
    for (int k = 0; k < CPG; ++k) ACCUMS(k, xv[k]);

    // degree 2 & 3: pair product (i<=j) feeds triples (a<=i<=j)
#pragma unroll
    for (int i = 0; i < CPG; ++i) {
#pragma unroll
        for (int j = i; j < CPG; ++j) {
            const vfloat4 p = xv[i] * xv[j];
            ACCUMS(8 + idx2(i, j), p);
#pragma unroll
            for (int a = 0; a <= i; ++a) {
                const vfloat4 t = xv[a] * p;
                ACCUMS(44 + idx3(a, i, j), t);
            }
        }
    }

#pragma unroll
    for (int o = 0; o < CPG; ++o) o4[(size_t)o * HU + q] = acc[o];
}

// ---------------------------------------------------------------------------
// Fallback (workspace too small): R3 kernel verbatim — known-good 68.5 us.
// ---------------------------------------------------------------------------
#define ACCUM(F, T) do {                                                       \
    const vfloat4 wa = *reinterpret_cast<const vfloat4*>(&wt[(F)][0]);         \
    const vfloat4 wb = *reinterpret_cast<const vfloat4*>(&wt[(F)][4]);         \
    acc[0] += wa.x * (T); acc[1] += wa.y * (T);                                \
    acc[2] += wa.z * (T); acc[3] += wa.w * (T);                                \
    acc[4] += wb.x * (T); acc[5] += wb.y * (T);                                \
    acc[6] += wb.z * (T); acc[7] += wb.w * (T);                                \
} while (0)
#define FENCE() __builtin_amdgcn_sched_barrier(0)

__global__ __launch_bounds__(256, 4) void hoaf_lds(
    const float* __restrict__ x,
    const float* __restrict__ w1, const float* __restrict__ b1,
    const float* __restrict__ w2, const float* __restrict__ b2,
    const float* __restrict__ w3, const float* __restrict__ b3,
    float* __restrict__ out)
{
    __shared__ __align__(16) float wt[165][8];

    const int tid   = threadIdx.x;
    const int g     = blockIdx.x;
    const int b     = blockIdx.y;
    const int chunk = blockIdx.z;

    for (int idx = tid; idx < 165 * 8; idx += 256) {
        const int f = idx >> 3, o = idx & 7;
        const int ch = g * CPG + o;
        float v;
        if (f < 8)        v = w1[ch * CPG + f];
        else if (f < 44)  v = w2[ch * N2 + (f - 8)];
        else if (f < 164) v = w3[ch * N3 + (f - 44)];
        else              v = b1[ch] + b2[ch] + b3[ch];
        wt[f][o] = v;
    }
    __syncthreads();

    const int q = tid + chunk * 256;
    if (q >= HU) return;

    const vfloat4 b_lo = *reinterpret_cast<const vfloat4*>(&wt[164][0]);
    const vfloat4 b_hi = *reinterpret_cast<const vfloat4*>(&wt[164][4]);

    const size_t base = ((size_t)(b * NGRP + g) * CPG) * HW;
    const vfloat4* x4 = (const vfloat4*)(x + base);
    vfloat4*       o4 = (vfloat4*)(out + base);

    vfloat4 xv[CPG];
#pragma unroll
    for (int c = 0; c < CPG; ++c) xv[c] = x4[(size_t)c * HU + q];

    vfloat4 acc[CPG];
    acc[0] = splat4(b_lo.x); acc[1] = splat4(b_lo.y);
    acc[2] = splat4(b_lo.z); acc[3] = splat4(b_lo.w);
    acc[4] = splat4(b_hi.x); acc[5] = splat4(b_hi.y);
    acc[6] = splat4(b_hi.z); acc[7] = splat4(b_hi.w);

#pragma unroll
    for (int k = 0; k < CPG; k += 2) {
        ACCUM(k, xv[k]);
        ACCUM(k + 1, xv[k + 1]);
        FENCE();
    }

#pragma unroll
    for (int i = 0; i < CPG; ++i) {
#pragma unroll
        for (int j = i; j < CPG; ++j) {
            const vfloat4 p = xv[i] * xv[j];
            ACCUM(8 + idx2(i, j), p);
#pragma unroll
            for (int a = 0; a <= i; ++a) {
                const vfloat4 t = xv[a] * p;
                ACCUM(44 + idx3(a, i, j), t);
            }
            FENCE();
        }
    }

#pragma unroll
    for (int o = 0; o < CPG; ++o) o4[(size_t)o * HU + q] = acc[o];
}

extern "C" void kernel_launch(void* const* d_in, const int* in_sizes, int n_in,
                              void* d_out, int out_size, void* d_ws, size_t ws_size,
                              hipStream_t stream) {
    const float* x  = (const float*)d_in[0];
    const float* w1 = (const float*)d_in[1];
    const float* b1 = (const float*)d_in[2];
    const float* w2 = (const float*)d_in[3];
    const float* b2 = (const float*)d_in[4];
    const float* w3 = (const float*)d_in[5];
    const float* b3 = (const float*)d_in[6];
    float* out = (float*)d_out;
    float* ws  = (float*)d_ws;

    dim3 grid(NGRP, NB, 4);   // (group, batch, pixel-chunk) — chunk slowest
    dim3 block(256);

    const size_t ws_needed = (size_t)NGRP * WSTRIDE * sizeof(float);  // 169 KB
    if (ws != nullptr && ws_size >= ws_needed) {
        prep_weights<<<dim3(NGRP), dim3(256), 0, stream>>>(w1, b1, w2, b2, w3, b3, ws);
        hoaf_sload<<<grid, block, 0, stream>>>(x, ws, out);
    } else {
        hoaf_lds<<<grid, block, 0, stream>>>(x, w1, b1, w2, b2, w3, b3, out);
    }
}